// Round 1
// baseline (857.649 us; speedup 1.0000x reference)
//
#include <hip/hip_runtime.h>
#include <hip/hip_bf16.h>
#include <cstdint>
#include <cstddef>

#define NN 4096

// ---------- preprocessing: column nnz counts (=deg) + 64-bit column-block bitmask ----------
__global__ __launch_bounds__(64) void k_prep(const float* __restrict__ K,
                                             unsigned* __restrict__ degc,
                                             unsigned long long* __restrict__ mask) {
  const int lane = threadIdx.x;        // 0..63 -> column within block
  const int db = blockIdx.x;           // 0..63 -> column block
  const int d = db * 64 + lane;
  const int s0 = blockIdx.y * 128;     // row chunk
  unsigned cnt = 0;
#pragma unroll 4
  for (int s = s0; s < s0 + 128; ++s) {
    const float kv = K[(size_t)s * NN + d];
    const bool nz = (kv != 0.0f);
    const unsigned long long b = __ballot(nz);
    cnt += nz ? 1u : 0u;
    if (lane == 0) mask[(size_t)s * 64 + db] = b;
  }
  atomicAdd(&degc[d], cnt);
}

__global__ __launch_bounds__(256) void k_dis(const unsigned* __restrict__ degc,
                                             float* __restrict__ dis) {
  const int d = blockIdx.x * 256 + threadIdx.x;
  dis[d] = rsqrtf((float)degc[d]);     // deg >= 1 always (diagonal nnz)
}

// ---------- layer input transform: g = dis[s]*(x@cw), xself = x@sw + sb + cb ----------
__global__ __launch_bounds__(256) void k_xform0(const float* __restrict__ K,
    const float* __restrict__ cw, const float* __restrict__ cb,
    const float* __restrict__ sw, const float* __restrict__ sb,
    const float* __restrict__ dis, float* __restrict__ g, float* __restrict__ xself) {
  const int c = threadIdx.x & 63;
  const int s = blockIdx.x * 4 + (threadIdx.x >> 6);
  const float xv = K[(size_t)s * NN + s];         // diag(K)
  g[(size_t)s * 64 + c] = dis[s] * xv * cw[c];
  xself[(size_t)s * 64 + c] = xv * sw[c] + sb[c] + cb[c];
}

__global__ __launch_bounds__(256) void k_xform(const float* __restrict__ xoutT,
    const float* __restrict__ sk, const float* __restrict__ cw, const float* __restrict__ cb,
    const float* __restrict__ sw, const float* __restrict__ sb,
    const float* __restrict__ dis, float* __restrict__ g, float* __restrict__ xself) {
  const int c = threadIdx.x & 63;
  const int s = blockIdx.x * 4 + (threadIdx.x >> 6);
  const float skv = sk[s];
  float accC = 0.f, accS = 0.f;
#pragma unroll 8
  for (int k = 0; k < 64; ++k) {
    const float xv = xoutT[(size_t)k * NN + s] + skv;  // x = x_out_prev + sk broadcast
    accC = fmaf(xv, cw[k * 64 + c], accC);
    accS = fmaf(xv, sw[k * 64 + c], accS);
  }
  g[(size_t)s * 64 + c] = dis[s] * accC;
  xself[(size_t)s * 64 + c] = accS + sb[c] + cb[c];
}

// ---------- masked aggregation: pacc[sc][c][d] = sum_{s in chunk, K[s][d]!=0} g[s][c] ----------
__global__ __launch_bounds__(256) void k_agg(const unsigned long long* __restrict__ mask,
    const float* __restrict__ g, float* __restrict__ pacc, int spc) {
  const int lane = threadIdx.x & 63;   // d within block
  const int wv = threadIdx.x >> 6;     // channel group
  const int db = blockIdx.x;
  const int d = db * 64 + lane;
  const unsigned long long lanebit = 1ull << lane;
  float acc[16];
#pragma unroll
  for (int j = 0; j < 16; ++j) acc[j] = 0.f;
  const int s0 = blockIdx.y * spc;
  const int s1 = s0 + spc;
#pragma unroll 4
  for (int s = s0; s < s1; ++s) {
    const unsigned long long m = mask[(size_t)s * 64 + db];   // uniform -> s_load
    const float b = (m & lanebit) ? 1.0f : 0.0f;
    const float4* gp = reinterpret_cast<const float4*>(g + (size_t)s * 64 + wv * 16);
    const float4 g0 = gp[0], g1 = gp[1], g2 = gp[2], g3 = gp[3];
    acc[0]  = fmaf(b, g0.x, acc[0]);  acc[1]  = fmaf(b, g0.y, acc[1]);
    acc[2]  = fmaf(b, g0.z, acc[2]);  acc[3]  = fmaf(b, g0.w, acc[3]);
    acc[4]  = fmaf(b, g1.x, acc[4]);  acc[5]  = fmaf(b, g1.y, acc[5]);
    acc[6]  = fmaf(b, g1.z, acc[6]);  acc[7]  = fmaf(b, g1.w, acc[7]);
    acc[8]  = fmaf(b, g2.x, acc[8]);  acc[9]  = fmaf(b, g2.y, acc[9]);
    acc[10] = fmaf(b, g2.z, acc[10]); acc[11] = fmaf(b, g2.w, acc[11]);
    acc[12] = fmaf(b, g3.x, acc[12]); acc[13] = fmaf(b, g3.y, acc[13]);
    acc[14] = fmaf(b, g3.z, acc[14]); acc[15] = fmaf(b, g3.w, acc[15]);
  }
  const size_t ob = ((size_t)blockIdx.y * 64 + (size_t)wv * 16) * NN + d;
#pragma unroll
  for (int j = 0; j < 16; ++j) pacc[ob + (size_t)j * NN] = acc[j];
}

// ---------- combine partials, finish x_out, cls score v = x_out@kw + kb ----------
__global__ __launch_bounds__(256) void k_combine(const float* __restrict__ pacc, int SC,
    const float* __restrict__ xself, const float* __restrict__ dis,
    const float* __restrict__ kw, const float* __restrict__ kb,
    float* __restrict__ xoutT, float* __restrict__ v) {
  __shared__ float red[4][64];
  const int lane = threadIdx.x & 63;
  const int wv = threadIdx.x >> 6;
  const int db = blockIdx.x;
  const int d = db * 64 + lane;
  const float dd = dis[d];
  float part = 0.f;
#pragma unroll
  for (int j = 0; j < 16; ++j) {
    const int c = wv * 16 + j;
    float a = 0.f;
    for (int sc2 = 0; sc2 < SC; ++sc2) a += pacc[((size_t)sc2 * 64 + c) * NN + d];
    const float xo = xself[(size_t)d * 64 + c] + dd * a;
    xoutT[(size_t)c * NN + d] = xo;
    part = fmaf(xo, kw[c], part);
  }
  red[wv][lane] = part;
  __syncthreads();
  if (wv == 0) v[d] = red[0][lane] + red[1][lane] + red[2][lane] + red[3][lane] + kb[0];
}

// ---------- log-domain Sinkhorn on a 64x64 matrix held in LDS ----------
__device__ __forceinline__ void sinkhorn_lds(float (*m)[65], int wv, int lane) {
  for (int it = 0; it < 20; ++it) {
    if ((it & 1) == 0) {          // row LSE (axis=1)
#pragma unroll
      for (int rr = 0; rr < 4; ++rr) {
        const int r = wv * 4 + rr;
        const float val = m[r][lane];
        float mx = val;
#pragma unroll
        for (int o = 32; o > 0; o >>= 1) mx = fmaxf(mx, __shfl_xor(mx, o, 64));
        float sm = __expf(val - mx);
#pragma unroll
        for (int o = 32; o > 0; o >>= 1) sm += __shfl_xor(sm, o, 64);
        m[r][lane] = val - mx - __logf(sm);
      }
    } else {                      // col LSE (axis=0)
#pragma unroll
      for (int cc = 0; cc < 4; ++cc) {
        const int c = wv * 4 + cc;
        const float val = m[lane][c];
        float mx = val;
#pragma unroll
        for (int o = 32; o > 0; o >>= 1) mx = fmaxf(mx, __shfl_xor(mx, o, 64));
        float sm = __expf(val - mx);
#pragma unroll
        for (int o = 32; o > 0; o >>= 1) sm += __shfl_xor(sm, o, 64);
        m[lane][c] = val - mx - __logf(sm);
      }
    }
    __syncthreads();
  }
}

__global__ __launch_bounds__(1024) void k_sinkhorn(const float* __restrict__ v,
                                                   float* __restrict__ sk) {
  __shared__ float m[64][65];
  const int tid = threadIdx.x, wv = tid >> 6, lane = tid & 63;
#pragma unroll
  for (int rr = 0; rr < 4; ++rr) { const int r = wv * 4 + rr; m[r][lane] = v[r * 64 + lane] * 20.0f; }
  __syncthreads();
  sinkhorn_lds(m, wv, lane);
#pragma unroll
  for (int rr = 0; rr < 4; ++rr) { const int r = wv * 4 + rr; sk[r * 64 + lane] = __expf(m[r][lane]); }
}

// ---------- final: scores = (x_out2+sk2)@fw + fb, transpose, Sinkhorn, write out ----------
__global__ __launch_bounds__(1024) void k_final(const float* __restrict__ xoutT,
    const float* __restrict__ sk, const float* __restrict__ fw, const float* __restrict__ fb,
    float* __restrict__ out) {
  __shared__ float m[64][65];
  const int tid = threadIdx.x, wv = tid >> 6, lane = tid & 63;
  const float fbv = fb[0];
#pragma unroll
  for (int q = 0; q < 4; ++q) {
    const int n = q * 1024 + tid;
    const float skv = sk[n];
    float acc = fbv;
#pragma unroll 8
    for (int k = 0; k < 64; ++k) acc = fmaf(xoutT[(size_t)k * NN + n] + skv, fw[k], acc);
    // s[r][c] = scores[c*64 + r]  (reshape(n2,n1).T) ; n = c*64+r
    m[n & 63][n >> 6] = acc * 20.0f;
  }
  __syncthreads();
  sinkhorn_lds(m, wv, lane);
#pragma unroll
  for (int rr = 0; rr < 4; ++rr) { const int r = wv * 4 + rr; out[r * 64 + lane] = __expf(m[r][lane]); }
}

extern "C" void kernel_launch(void* const* d_in, const int* in_sizes, int n_in,
                              void* d_out, int out_size, void* d_ws, size_t ws_size,
                              hipStream_t stream) {
  const float* K = (const float*)d_in[0];
  // d_in[1]=edge_index (redundant: == nonzero(K)), d_in[2]=n1, d_in[3]=n2 (both 64)
  const float* cw[3] = {(const float*)d_in[4],  (const float*)d_in[10], (const float*)d_in[16]};
  const float* cb[3] = {(const float*)d_in[5],  (const float*)d_in[11], (const float*)d_in[17]};
  const float* sw[3] = {(const float*)d_in[6],  (const float*)d_in[12], (const float*)d_in[18]};
  const float* sb[3] = {(const float*)d_in[7],  (const float*)d_in[13], (const float*)d_in[19]};
  const float* kw[3] = {(const float*)d_in[8],  (const float*)d_in[14], (const float*)d_in[20]};
  const float* kb[3] = {(const float*)d_in[9],  (const float*)d_in[15], (const float*)d_in[21]};
  const float* fw = (const float*)d_in[22];
  const float* fb = (const float*)d_in[23];
  float* out = (float*)d_out;

  char* ws = (char*)d_ws;
  const size_t MB = 1024 * 1024;
  unsigned* degc            = (unsigned*)(ws + 0);
  float* dis                = (float*)(ws + 0x4000);
  float* v                  = (float*)(ws + 0x8000);
  float* sk                 = (float*)(ws + 0xC000);
  unsigned long long* mask  = (unsigned long long*)(ws + 0x10000);          // 2 MB
  float* g                  = (float*)(ws + 0x10000 + 2 * MB);              // 1 MB
  float* xself              = (float*)(ws + 0x10000 + 3 * MB);              // 1 MB
  float* xoutT              = (float*)(ws + 0x10000 + 4 * MB);              // 1 MB
  float* pacc               = (float*)(ws + 0x10000 + 5 * MB);              // SC MB

  int SC = 16;
  while (SC > 1 && (size_t)0x10000 + (5 + (size_t)SC) * MB > ws_size) SC >>= 1;
  const int spc = NN / SC;

  hipMemsetAsync(degc, 0, NN * sizeof(unsigned), stream);
  k_prep<<<dim3(64, 32), 64, 0, stream>>>(K, degc, mask);
  k_dis<<<16, 256, 0, stream>>>(degc, dis);

  for (int l = 0; l < 3; ++l) {
    if (l == 0) k_xform0<<<1024, 256, 0, stream>>>(K, cw[0], cb[0], sw[0], sb[0], dis, g, xself);
    else        k_xform <<<1024, 256, 0, stream>>>(xoutT, sk, cw[l], cb[l], sw[l], sb[l], dis, g, xself);
    k_agg<<<dim3(64, SC), 256, 0, stream>>>(mask, g, pacc, spc);
    k_combine<<<64, 256, 0, stream>>>(pacc, SC, xself, dis, kw[l], kb[l], xoutT, v);
    k_sinkhorn<<<1, 1024, 0, stream>>>(v, sk);
  }
  k_final<<<1, 1024, 0, stream>>>(xoutT, sk, fw, fb, out);
}

// Round 2
// 498.505 us; speedup vs baseline: 1.7204x; 1.7204x over previous
//
#include <hip/hip_runtime.h>
#include <hip/hip_bf16.h>
#include <cstdint>
#include <cstddef>

#define NN 4096

typedef float f32x4 __attribute__((ext_vector_type(4)));
typedef short s16x8 __attribute__((ext_vector_type(8)));

// ---------- prep: bit-plane mask maskT[chunk][d] (bits = s within chunk), deg, diag ----------
__global__ __launch_bounds__(256) void k_prep(const float* __restrict__ K,
    unsigned* __restrict__ degc, unsigned long long* __restrict__ maskT,
    float* __restrict__ xdiag) {
  const int lane = threadIdx.x & 63;
  const int wv = threadIdx.x >> 6;
  const int d = blockIdx.x * 64 + lane;
  const int sbase = blockIdx.y * 256 + wv * 64;   // this wave's 64-row chunk
  unsigned long long w = 0;
#pragma unroll 8
  for (int i = 0; i < 64; ++i) {
    const int s = sbase + i;
    const float kv = K[(size_t)s * NN + d];
    w |= ((unsigned long long)(kv != 0.0f)) << i;  // each lane tracks its own column
    if (s == d) xdiag[d] = kv;                     // diag(K) node features
  }
  maskT[(size_t)(blockIdx.y * 4 + wv) * NN + d] = w;   // coalesced 512B per wave
  atomicAdd(&degc[d], (unsigned)__popcll(w));
}

__global__ __launch_bounds__(256) void k_dis(const unsigned* __restrict__ degc,
                                             float* __restrict__ dis) {
  const int d = blockIdx.x * 256 + threadIdx.x;
  dis[d] = rsqrtf((float)degc[d]);                 // deg >= 1 (diag nnz)
}

// ---------- layer-0 transform: g = dis*x*cw (split bf16, [c][s]), xselfT = x*sw+sb+cb ----------
__global__ __launch_bounds__(256) void k_xform0(const float* __restrict__ xdiag,
    const float* __restrict__ dis,
    const float* __restrict__ cw, const float* __restrict__ cb,
    const float* __restrict__ sw, const float* __restrict__ sb,
    __hip_bfloat16* __restrict__ gHi, __hip_bfloat16* __restrict__ gLo,
    float* __restrict__ xselfT) {
  const int lane = threadIdx.x & 63;
  const int wv = threadIdx.x >> 6;
  const int s = blockIdx.x * 64 + lane;
  const float xv = xdiag[s];
  const float ds = dis[s];
#pragma unroll
  for (int i = 0; i < 16; ++i) {
    const int c = wv * 16 + i;
    const float gv = ds * xv * cw[c];
    const __hip_bfloat16 hi = __float2bfloat16(gv);
    gHi[(size_t)c * NN + s] = hi;
    gLo[(size_t)c * NN + s] = __float2bfloat16(gv - __bfloat162float(hi));
    xselfT[(size_t)c * NN + s] = xv * sw[c] + sb[c] + cb[c];
  }
}

// ---------- layer 1/2 transform: x = xoutT + sk; g = dis*(x@cw); xselfT = x@sw+sb+cb ----------
__global__ __launch_bounds__(256) void k_xform(const float* __restrict__ xoutT,
    const float* __restrict__ sk, const float* __restrict__ dis,
    const float* __restrict__ cw, const float* __restrict__ cb,
    const float* __restrict__ sw, const float* __restrict__ sb,
    __hip_bfloat16* __restrict__ gHi, __hip_bfloat16* __restrict__ gLo,
    float* __restrict__ xselfT) {
  __shared__ float xt[64][64];                     // [k][s-local]
  const int lane = threadIdx.x & 63;
  const int wv = threadIdx.x >> 6;
  const int s = blockIdx.x * 64 + lane;
  const float skv = sk[s];
#pragma unroll
  for (int i = 0; i < 16; ++i) {
    const int k = wv * 16 + i;
    xt[k][lane] = xoutT[(size_t)k * NN + s] + skv;  // coalesced load, clean LDS write
  }
  __syncthreads();
  float accC[16], accS[16];
#pragma unroll
  for (int i = 0; i < 16; ++i) { accC[i] = 0.f; accS[i] = 0.f; }
  for (int k = 0; k < 64; ++k) {
    const float xv = xt[k][lane];
#pragma unroll
    for (int i = 0; i < 16; ++i) {
      const int c = wv * 16 + i;
      accC[i] = fmaf(xv, cw[k * 64 + c], accC[i]);  // cw uniform -> s_load
      accS[i] = fmaf(xv, sw[k * 64 + c], accS[i]);
    }
  }
  const float ds = dis[s];
#pragma unroll
  for (int i = 0; i < 16; ++i) {
    const int c = wv * 16 + i;
    const float gv = ds * accC[i];
    const __hip_bfloat16 hi = __float2bfloat16(gv);
    gHi[(size_t)c * NN + s] = hi;
    gLo[(size_t)c * NN + s] = __float2bfloat16(gv - __bfloat162float(hi));
    xselfT[(size_t)c * NN + s] = accS[i] + sb[c] + cb[c];
  }
}

// ---------- MFMA masked aggregation + fused combine + cls score ----------
// aggT[c][d] = sum_s bit(s,d) * g[s][c];  xoutT = xselfT + dis[d]*aggT;  v = xoutT@kw + kb
__global__ __launch_bounds__(512) void k_agg(const unsigned long long* __restrict__ maskT,
    const __hip_bfloat16* __restrict__ gHi, const __hip_bfloat16* __restrict__ gLo,
    const float* __restrict__ xselfT, const float* __restrict__ dis,
    const float* __restrict__ kw, const float* __restrict__ kb,
    float* __restrict__ xoutT, float* __restrict__ v) {
  const int tid = threadIdx.x;
  const int lane = tid & 63;
  const int wv = tid >> 6;           // 0..7
  const int mtile = wv & 3;          // channel 16-group
  const int nhalf = wv >> 2;         // 0/1 -> which 16 d's
  const int l15 = lane & 15;
  const int h = lane >> 4;           // 0..3
  const int d = blockIdx.x * 32 + nhalf * 16 + l15;
  const int ch = mtile * 16 + l15;   // A-operand row (channel)
  const short* __restrict__ gh = (const short*)gHi;
  const short* __restrict__ gl = (const short*)gLo;
  f32x4 acc = {0.f, 0.f, 0.f, 0.f};
#pragma unroll 4
  for (int c = 0; c < 64; ++c) {     // 64-s chunk
    const unsigned long long w = maskT[(size_t)c * NN + d];   // coalesced per wave
    const unsigned half0 = (unsigned)w, half1 = (unsigned)(w >> 32);
#pragma unroll
    for (int t = 0; t < 2; ++t) {    // two K=32 MFMA steps per chunk
      const unsigned half = t ? half1 : half0;
      const unsigned hb = (half >> (8 * h)) & 0xFFu;
      s16x8 bfr;
#pragma unroll
      for (int j = 0; j < 8; ++j)
        bfr[j] = (short)(((hb >> j) & 1u) * 0x3F80u);         // bit -> bf16 1.0/0.0
      const size_t abase = (size_t)ch * NN + (size_t)(c * 64 + t * 32 + 8 * h);
      const s16x8 ah = *(const s16x8*)(gh + abase);
      const s16x8 al = *(const s16x8*)(gl + abase);
      acc = __builtin_amdgcn_mfma_f32_16x16x32_bf16(ah, bfr, acc, 0, 0, 0);
      acc = __builtin_amdgcn_mfma_f32_16x16x32_bf16(al, bfr, acc, 0, 0, 0);
    }
  }
  // epilogue: C/D layout col=lane&15 (=d), row=(lane>>4)*4+reg (=channel within mtile)
  __shared__ float vred[2][16][17];
  const float dd = dis[d];
  float p = 0.f;
#pragma unroll
  for (int r = 0; r < 4; ++r) {
    const int chr = mtile * 16 + h * 4 + r;
    const float xo = xselfT[(size_t)chr * NN + d] + dd * acc[r];
    xoutT[(size_t)chr * NN + d] = xo;
    p = fmaf(xo, kw[chr], p);
  }
  vred[nhalf][l15][mtile * 4 + h] = p;
  __syncthreads();
  if (tid < 32) {
    const int dl = tid & 15, nh = tid >> 4;
    float sum = kb[0];
#pragma unroll
    for (int q = 0; q < 16; ++q) sum += vred[nh][dl][q];
    v[blockIdx.x * 32 + nh * 16 + dl] = sum;
  }
}

// ---------- log-domain Sinkhorn on a 64x64 matrix in LDS ----------
__device__ __forceinline__ void sinkhorn_lds(float (*m)[65], int wv, int lane) {
  for (int it = 0; it < 20; ++it) {
    if ((it & 1) == 0) {
#pragma unroll
      for (int rr = 0; rr < 4; ++rr) {
        const int r = wv * 4 + rr;
        const float val = m[r][lane];
        float mx = val;
#pragma unroll
        for (int o = 32; o > 0; o >>= 1) mx = fmaxf(mx, __shfl_xor(mx, o, 64));
        float sm = __expf(val - mx);
#pragma unroll
        for (int o = 32; o > 0; o >>= 1) sm += __shfl_xor(sm, o, 64);
        m[r][lane] = val - mx - __logf(sm);
      }
    } else {
#pragma unroll
      for (int cc = 0; cc < 4; ++cc) {
        const int c = wv * 4 + cc;
        const float val = m[lane][c];
        float mx = val;
#pragma unroll
        for (int o = 32; o > 0; o >>= 1) mx = fmaxf(mx, __shfl_xor(mx, o, 64));
        float sm = __expf(val - mx);
#pragma unroll
        for (int o = 32; o > 0; o >>= 1) sm += __shfl_xor(sm, o, 64);
        m[lane][c] = val - mx - __logf(sm);
      }
    }
    __syncthreads();
  }
}

__global__ __launch_bounds__(1024) void k_sinkhorn(const float* __restrict__ v,
                                                   float* __restrict__ sk) {
  __shared__ float m[64][65];
  const int tid = threadIdx.x, wv = tid >> 6, lane = tid & 63;
#pragma unroll
  for (int rr = 0; rr < 4; ++rr) { const int r = wv * 4 + rr; m[r][lane] = v[r * 64 + lane] * 20.0f; }
  __syncthreads();
  sinkhorn_lds(m, wv, lane);
#pragma unroll
  for (int rr = 0; rr < 4; ++rr) { const int r = wv * 4 + rr; sk[r * 64 + lane] = __expf(m[r][lane]); }
}

// ---------- final: scores = (x_out2+sk2)@fw + fb, transpose, Sinkhorn, out ----------
__global__ __launch_bounds__(1024) void k_final(const float* __restrict__ xoutT,
    const float* __restrict__ sk, const float* __restrict__ fw, const float* __restrict__ fb,
    float* __restrict__ out) {
  __shared__ float m[64][65];
  const int tid = threadIdx.x, wv = tid >> 6, lane = tid & 63;
  const float fbv = fb[0];
#pragma unroll
  for (int q = 0; q < 4; ++q) {
    const int n = q * 1024 + tid;
    const float skv = sk[n];
    float acc = fbv;
#pragma unroll 8
    for (int k = 0; k < 64; ++k) acc = fmaf(xoutT[(size_t)k * NN + n] + skv, fw[k], acc);
    m[n & 63][n >> 6] = acc * 20.0f;   // s[i1][i2] = scores[i2*64+i1]
  }
  __syncthreads();
  sinkhorn_lds(m, wv, lane);
#pragma unroll
  for (int rr = 0; rr < 4; ++rr) { const int r = wv * 4 + rr; out[r * 64 + lane] = __expf(m[r][lane]); }
}

extern "C" void kernel_launch(void* const* d_in, const int* in_sizes, int n_in,
                              void* d_out, int out_size, void* d_ws, size_t ws_size,
                              hipStream_t stream) {
  const float* K = (const float*)d_in[0];
  const float* cw[3] = {(const float*)d_in[4],  (const float*)d_in[10], (const float*)d_in[16]};
  const float* cb[3] = {(const float*)d_in[5],  (const float*)d_in[11], (const float*)d_in[17]};
  const float* sw[3] = {(const float*)d_in[6],  (const float*)d_in[12], (const float*)d_in[18]};
  const float* sb[3] = {(const float*)d_in[7],  (const float*)d_in[13], (const float*)d_in[19]};
  const float* kw[3] = {(const float*)d_in[8],  (const float*)d_in[14], (const float*)d_in[20]};
  const float* kb[3] = {(const float*)d_in[9],  (const float*)d_in[15], (const float*)d_in[21]};
  const float* fw = (const float*)d_in[22];
  const float* fb = (const float*)d_in[23];
  float* out = (float*)d_out;

  char* ws = (char*)d_ws;
  const size_t KB = 1024, MB = 1024 * 1024;
  unsigned* degc           = (unsigned*)(ws + 0);                 // 16 KB
  float* dis               = (float*)(ws + 16 * KB);              // 16 KB
  float* xdiag             = (float*)(ws + 32 * KB);              // 16 KB
  float* v                 = (float*)(ws + 48 * KB);              // 16 KB
  float* sk                = (float*)(ws + 64 * KB);              // 16 KB
  unsigned long long* maskT= (unsigned long long*)(ws + 128 * KB);// 2 MB
  __hip_bfloat16* gHi      = (__hip_bfloat16*)(ws + 128 * KB + 2 * MB);          // 512 KB
  __hip_bfloat16* gLo      = (__hip_bfloat16*)(ws + 128 * KB + 2 * MB + 512 * KB);// 512 KB
  float* xselfT            = (float*)(ws + 128 * KB + 3 * MB);    // 1 MB
  float* xoutT             = (float*)(ws + 128 * KB + 4 * MB);    // 1 MB
  (void)in_sizes; (void)n_in; (void)out_size; (void)ws_size;

  hipMemsetAsync(degc, 0, NN * sizeof(unsigned), stream);
  k_prep<<<dim3(64, 16), 256, 0, stream>>>(K, degc, maskT, xdiag);
  k_dis<<<16, 256, 0, stream>>>(degc, dis);

  for (int l = 0; l < 3; ++l) {
    if (l == 0)
      k_xform0<<<64, 256, 0, stream>>>(xdiag, dis, cw[0], cb[0], sw[0], sb[0], gHi, gLo, xselfT);
    else
      k_xform<<<64, 256, 0, stream>>>(xoutT, sk, dis, cw[l], cb[l], sw[l], sb[l], gHi, gLo, xselfT);
    k_agg<<<128, 512, 0, stream>>>(maskT, gHi, gLo, xselfT, dis, kw[l], kb[l], xoutT, v);
    k_sinkhorn<<<1, 1024, 0, stream>>>(v, sk);
  }
  k_final<<<1, 1024, 0, stream>>>(xoutT, sk, fw, fb, out);
}

// Round 3
// 478.719 us; speedup vs baseline: 1.7916x; 1.0413x over previous
//
#include <hip/hip_runtime.h>
#include <hip/hip_bf16.h>
#include <cstdint>
#include <cstddef>

#define NN 4096

typedef float f32x4 __attribute__((ext_vector_type(4)));
typedef short s16x8 __attribute__((ext_vector_type(8)));

// ---------- prep: bit-plane mask maskT[chunk][d] (bit i = row sbase+i), deg counts ----------
__global__ __launch_bounds__(256) void k_prep(const float* __restrict__ K,
    unsigned* __restrict__ degc, unsigned long long* __restrict__ maskT) {
  const int lane = threadIdx.x & 63;
  const int wv = threadIdx.x >> 6;
  const int d0 = blockIdx.x * 256 + lane * 4;      // each lane owns 4 columns
  const int sbase = blockIdx.y * 256 + wv * 64;    // this wave's 64-row chunk
  const int chunk = blockIdx.y * 4 + wv;
  unsigned long long w0 = 0, w1 = 0, w2 = 0, w3 = 0;
#pragma unroll 8
  for (int i = 0; i < 64; ++i) {
    const float4 kv = *(const float4*)(K + (size_t)(sbase + i) * NN + d0);
    w0 |= ((unsigned long long)(kv.x != 0.0f)) << i;
    w1 |= ((unsigned long long)(kv.y != 0.0f)) << i;
    w2 |= ((unsigned long long)(kv.z != 0.0f)) << i;
    w3 |= ((unsigned long long)(kv.w != 0.0f)) << i;
  }
  unsigned long long* mp = maskT + (size_t)chunk * NN + d0;
  mp[0] = w0; mp[1] = w1; mp[2] = w2; mp[3] = w3;
  atomicAdd(&degc[d0 + 0], (unsigned)__popcll(w0));
  atomicAdd(&degc[d0 + 1], (unsigned)__popcll(w1));
  atomicAdd(&degc[d0 + 2], (unsigned)__popcll(w2));
  atomicAdd(&degc[d0 + 3], (unsigned)__popcll(w3));
}

// ---------- layer-0 transform: g = dis*diag(K)*cw (split bf16, [c][s]), xselfT ----------
__global__ __launch_bounds__(256) void k_xform0(const float* __restrict__ K,
    const unsigned* __restrict__ degc,
    const float* __restrict__ cw, const float* __restrict__ cb,
    const float* __restrict__ sw, const float* __restrict__ sb,
    __hip_bfloat16* __restrict__ gHi, __hip_bfloat16* __restrict__ gLo,
    float* __restrict__ xselfT) {
  const int lane = threadIdx.x & 63;
  const int wv = threadIdx.x >> 6;
  const int s = blockIdx.x * 64 + lane;
  const float xv = K[(size_t)s * NN + s];          // diag(K)
  const float ds = rsqrtf((float)degc[s]);
#pragma unroll
  for (int i = 0; i < 16; ++i) {
    const int c = wv * 16 + i;
    const float gv = ds * xv * cw[c];
    const __hip_bfloat16 hi = __float2bfloat16(gv);
    gHi[(size_t)c * NN + s] = hi;
    gLo[(size_t)c * NN + s] = __float2bfloat16(gv - __bfloat162float(hi));
    xselfT[(size_t)c * NN + s] = xv * sw[c] + sb[c] + cb[c];
  }
}

// ---------- layer 1/2 transform: x = xoutT + sk; g = dis*(x@cw); xselfT = x@sw+sb+cb ----------
__global__ __launch_bounds__(256) void k_xform(const float* __restrict__ xoutT,
    const float* __restrict__ sk, const unsigned* __restrict__ degc,
    const float* __restrict__ cw, const float* __restrict__ cb,
    const float* __restrict__ sw, const float* __restrict__ sb,
    __hip_bfloat16* __restrict__ gHi, __hip_bfloat16* __restrict__ gLo,
    float* __restrict__ xselfT) {
  __shared__ float xt[64][64];                     // [k][s-local]
  const int lane = threadIdx.x & 63;
  const int wv = threadIdx.x >> 6;
  const int s = blockIdx.x * 64 + lane;
  const float skv = sk[s];
#pragma unroll
  for (int i = 0; i < 16; ++i) {
    const int k = wv * 16 + i;
    xt[k][lane] = xoutT[(size_t)k * NN + s] + skv; // coalesced
  }
  __syncthreads();
  const int cbase = blockIdx.y * 32 + wv * 8;
  float accC[8], accS[8];
#pragma unroll
  for (int i = 0; i < 8; ++i) { accC[i] = 0.f; accS[i] = 0.f; }
  for (int k = 0; k < 64; ++k) {
    const float xv = xt[k][lane];
#pragma unroll
    for (int i = 0; i < 8; ++i) {
      accC[i] = fmaf(xv, cw[k * 64 + cbase + i], accC[i]);
      accS[i] = fmaf(xv, sw[k * 64 + cbase + i], accS[i]);
    }
  }
  const float ds = rsqrtf((float)degc[s]);
#pragma unroll
  for (int i = 0; i < 8; ++i) {
    const int c = cbase + i;
    const float gv = ds * accC[i];
    const __hip_bfloat16 hi = __float2bfloat16(gv);
    gHi[(size_t)c * NN + s] = hi;
    gLo[(size_t)c * NN + s] = __float2bfloat16(gv - __bfloat162float(hi));
    xselfT[(size_t)c * NN + s] = accS[i] + sb[c] + cb[c];
  }
}

// ---------- MFMA masked aggregation, split-K partials ----------
// pacc[kb][c][d] = sum_{s in K-chunk kb} bit(s,d) * g[s][c]
__global__ __launch_bounds__(512) void k_agg(const unsigned long long* __restrict__ maskT,
    const __hip_bfloat16* __restrict__ gHi, const __hip_bfloat16* __restrict__ gLo,
    float* __restrict__ pacc, int cpk) {
  const int tid = threadIdx.x;
  const int lane = tid & 63;
  const int wv = tid >> 6;           // 0..7
  const int mtile = wv & 3;          // channel 16-group
  const int nhalf = wv >> 2;         // which 16 d's
  const int l15 = lane & 15;
  const int h = lane >> 4;           // 0..3
  const int d = blockIdx.x * 32 + nhalf * 16 + l15;
  const int ch = mtile * 16 + l15;   // A-operand row (channel)
  const int c0 = blockIdx.y * cpk;
  const short* __restrict__ gh = (const short*)gHi;
  const short* __restrict__ gl = (const short*)gLo;
  f32x4 acch = {0.f, 0.f, 0.f, 0.f};
  f32x4 accl = {0.f, 0.f, 0.f, 0.f};
#pragma unroll 4
  for (int c = c0; c < c0 + cpk; ++c) {
    const unsigned long long w = maskT[(size_t)c * NN + d];
    const unsigned half0 = (unsigned)w, half1 = (unsigned)(w >> 32);
#pragma unroll
    for (int t = 0; t < 2; ++t) {
      const unsigned half = t ? half1 : half0;
      const unsigned hb = (half >> (8 * h)) & 0xFFu;
      s16x8 bfr;
#pragma unroll
      for (int j = 0; j < 8; ++j)
        bfr[j] = (short)(((hb >> j) & 1u) * 0x3F80u);   // bit -> bf16 1.0/0.0
      const size_t abase = (size_t)ch * NN + (size_t)(c * 64 + t * 32 + 8 * h);
      const s16x8 ah = *(const s16x8*)(gh + abase);
      const s16x8 al = *(const s16x8*)(gl + abase);
      acch = __builtin_amdgcn_mfma_f32_16x16x32_bf16(ah, bfr, acch, 0, 0, 0);  // independent
      accl = __builtin_amdgcn_mfma_f32_16x16x32_bf16(al, bfr, accl, 0, 0, 0);  // chains
    }
  }
  // C/D layout: col = lane&15 (=d), row = (lane>>4)*4 + reg (=channel within mtile)
#pragma unroll
  for (int r = 0; r < 4; ++r) {
    const int chr = mtile * 16 + h * 4 + r;
    pacc[((size_t)blockIdx.y * 64 + chr) * NN + d] = acch[r] + accl[r];
  }
}

// ---------- combine partials + xself + dis, cls score v ----------
__global__ __launch_bounds__(256) void k_combine(const float* __restrict__ pacc, int nkb,
    const float* __restrict__ xselfT, const unsigned* __restrict__ degc,
    const float* __restrict__ kw, const float* __restrict__ kb,
    float* __restrict__ xoutT, float* __restrict__ v) {
  __shared__ float red[4][64];
  const int lane = threadIdx.x & 63;
  const int wv = threadIdx.x >> 6;
  const int d = blockIdx.x * 64 + lane;
  const float dd = rsqrtf((float)degc[d]);
  float p = 0.f;
#pragma unroll
  for (int i = 0; i < 16; ++i) {
    const int c = wv * 16 + i;
    float a = 0.f;
    for (int k2 = 0; k2 < nkb; ++k2) a += pacc[((size_t)k2 * 64 + c) * NN + d];
    const float xo = xselfT[(size_t)c * NN + d] + dd * a;
    xoutT[(size_t)c * NN + d] = xo;
    p = fmaf(xo, kw[c], p);
  }
  red[wv][lane] = p;
  __syncthreads();
  if (wv == 0) v[d] = red[0][lane] + red[1][lane] + red[2][lane] + red[3][lane] + kb[0];
}

// ---------- log-domain Sinkhorn on a 64x64 matrix in LDS ----------
__device__ __forceinline__ void sinkhorn_lds(float (*m)[65], int wv, int lane) {
  for (int it = 0; it < 20; ++it) {
    if ((it & 1) == 0) {
#pragma unroll
      for (int rr = 0; rr < 4; ++rr) {
        const int r = wv * 4 + rr;
        const float val = m[r][lane];
        float mx = val;
#pragma unroll
        for (int o = 32; o > 0; o >>= 1) mx = fmaxf(mx, __shfl_xor(mx, o, 64));
        float sm = __expf(val - mx);
#pragma unroll
        for (int o = 32; o > 0; o >>= 1) sm += __shfl_xor(sm, o, 64);
        m[r][lane] = val - mx - __logf(sm);
      }
    } else {
#pragma unroll
      for (int cc = 0; cc < 4; ++cc) {
        const int c = wv * 4 + cc;
        const float val = m[lane][c];
        float mx = val;
#pragma unroll
        for (int o = 32; o > 0; o >>= 1) mx = fmaxf(mx, __shfl_xor(mx, o, 64));
        float sm = __expf(val - mx);
#pragma unroll
        for (int o = 32; o > 0; o >>= 1) sm += __shfl_xor(sm, o, 64);
        m[lane][c] = val - mx - __logf(sm);
      }
    }
    __syncthreads();
  }
}

__global__ __launch_bounds__(1024) void k_sinkhorn(const float* __restrict__ v,
                                                   float* __restrict__ sk) {
  __shared__ float m[64][65];
  const int tid = threadIdx.x, wv = tid >> 6, lane = tid & 63;
#pragma unroll
  for (int rr = 0; rr < 4; ++rr) { const int r = wv * 4 + rr; m[r][lane] = v[r * 64 + lane] * 20.0f; }
  __syncthreads();
  sinkhorn_lds(m, wv, lane);
#pragma unroll
  for (int rr = 0; rr < 4; ++rr) { const int r = wv * 4 + rr; sk[r * 64 + lane] = __expf(m[r][lane]); }
}

// ---------- final: scores = (x_out2+sk2)@fw + fb, transpose, Sinkhorn, out ----------
__global__ __launch_bounds__(1024) void k_final(const float* __restrict__ xoutT,
    const float* __restrict__ sk, const float* __restrict__ fw, const float* __restrict__ fb,
    float* __restrict__ out) {
  __shared__ float m[64][65];
  const int tid = threadIdx.x, wv = tid >> 6, lane = tid & 63;
  const float fbv = fb[0];
#pragma unroll
  for (int q = 0; q < 4; ++q) {
    const int n = q * 1024 + tid;
    const float skv = sk[n];
    float acc = fbv;
#pragma unroll 8
    for (int k = 0; k < 64; ++k) acc = fmaf(xoutT[(size_t)k * NN + n] + skv, fw[k], acc);
    m[n & 63][n >> 6] = acc * 20.0f;   // s[i1][i2] = scores[i2*64+i1]
  }
  __syncthreads();
  sinkhorn_lds(m, wv, lane);
#pragma unroll
  for (int rr = 0; rr < 4; ++rr) { const int r = wv * 4 + rr; out[r * 64 + lane] = __expf(m[r][lane]); }
}

extern "C" void kernel_launch(void* const* d_in, const int* in_sizes, int n_in,
                              void* d_out, int out_size, void* d_ws, size_t ws_size,
                              hipStream_t stream) {
  const float* K = (const float*)d_in[0];
  const float* cw[3] = {(const float*)d_in[4],  (const float*)d_in[10], (const float*)d_in[16]};
  const float* cb[3] = {(const float*)d_in[5],  (const float*)d_in[11], (const float*)d_in[17]};
  const float* sw[3] = {(const float*)d_in[6],  (const float*)d_in[12], (const float*)d_in[18]};
  const float* sb[3] = {(const float*)d_in[7],  (const float*)d_in[13], (const float*)d_in[19]};
  const float* kw[3] = {(const float*)d_in[8],  (const float*)d_in[14], (const float*)d_in[20]};
  const float* kb[3] = {(const float*)d_in[9],  (const float*)d_in[15], (const float*)d_in[21]};
  const float* fw = (const float*)d_in[22];
  const float* fb = (const float*)d_in[23];
  float* out = (float*)d_out;

  char* ws = (char*)d_ws;
  const size_t KB = 1024, MB = 1024 * 1024;
  unsigned* degc            = (unsigned*)(ws + 0);                // 16 KB
  float* v                  = (float*)(ws + 16 * KB);             // 16 KB
  float* sk                 = (float*)(ws + 32 * KB);             // 16 KB
  unsigned long long* maskT = (unsigned long long*)(ws + 64 * KB);// 2 MB
  __hip_bfloat16* gHi       = (__hip_bfloat16*)(ws + 64 * KB + 2 * MB);            // 512 KB
  __hip_bfloat16* gLo       = (__hip_bfloat16*)(ws + 64 * KB + 2 * MB + 512 * KB); // 512 KB
  float* xselfT             = (float*)(ws + 64 * KB + 3 * MB);    // 1 MB
  float* xoutT              = (float*)(ws + 64 * KB + 4 * MB);    // 1 MB
  float* pacc               = (float*)(ws + 64 * KB + 5 * MB);    // NKB MB
  (void)in_sizes; (void)n_in; (void)out_size;

  int NKB = 8;
  while (NKB > 1 && 64 * KB + (5 + (size_t)NKB) * MB > ws_size) NKB >>= 1;
  const int cpk = 64 / NKB;

  hipMemsetAsync(degc, 0, NN * sizeof(unsigned), stream);
  k_prep<<<dim3(16, 16), 256, 0, stream>>>(K, degc, maskT);

  for (int l = 0; l < 3; ++l) {
    if (l == 0)
      k_xform0<<<64, 256, 0, stream>>>(K, degc, cw[0], cb[0], sw[0], sb[0], gHi, gLo, xselfT);
    else
      k_xform<<<dim3(64, 2), 256, 0, stream>>>(xoutT, sk, degc, cw[l], cb[l], sw[l], sb[l], gHi, gLo, xselfT);
    k_agg<<<dim3(128, NKB), 512, 0, stream>>>(maskT, gHi, gLo, pacc, cpk);
    k_combine<<<64, 256, 0, stream>>>(pacc, NKB, xselfT, degc, kw[l], kb[l], xoutT, v);
    k_sinkhorn<<<1, 1024, 0, stream>>>(v, sk);
  }
  k_final<<<1, 1024, 0, stream>>>(xoutT, sk, fw, fb, out);
}

// Round 4
// 333.200 us; speedup vs baseline: 2.5740x; 1.4367x over previous
//
#include <hip/hip_runtime.h>
#include <hip/hip_bf16.h>
#include <cstdint>
#include <cstddef>

#define NN 4096

typedef float f32x4 __attribute__((ext_vector_type(4)));
typedef short s16x8 __attribute__((ext_vector_type(8)));

// ---------- prep: bit-plane mask maskT[chunk][d] (bit i = row sbase+i), deg counts ----------
__global__ __launch_bounds__(256) void k_prep(const float* __restrict__ K,
    unsigned* __restrict__ degc, unsigned long long* __restrict__ maskT) {
  const int lane = threadIdx.x & 63;
  const int wv = threadIdx.x >> 6;
  const int d0 = blockIdx.x * 256 + lane * 4;      // each lane owns 4 columns
  const int sbase = blockIdx.y * 256 + wv * 64;    // this wave's 64-row chunk
  const int chunk = blockIdx.y * 4 + wv;
  unsigned long long w0 = 0, w1 = 0, w2 = 0, w3 = 0;
#pragma unroll 8
  for (int i = 0; i < 64; ++i) {
    const float4 kv = *(const float4*)(K + (size_t)(sbase + i) * NN + d0);
    w0 |= ((unsigned long long)(kv.x != 0.0f)) << i;
    w1 |= ((unsigned long long)(kv.y != 0.0f)) << i;
    w2 |= ((unsigned long long)(kv.z != 0.0f)) << i;
    w3 |= ((unsigned long long)(kv.w != 0.0f)) << i;
  }
  unsigned long long* mp = maskT + (size_t)chunk * NN + d0;
  mp[0] = w0; mp[1] = w1; mp[2] = w2; mp[3] = w3;
  atomicAdd(&degc[d0 + 0], (unsigned)__popcll(w0));
  atomicAdd(&degc[d0 + 1], (unsigned)__popcll(w1));
  atomicAdd(&degc[d0 + 2], (unsigned)__popcll(w2));
  atomicAdd(&degc[d0 + 3], (unsigned)__popcll(w3));
}

// ---------- layer-0 transform ----------
__global__ __launch_bounds__(256) void k_xform0(const float* __restrict__ K,
    const unsigned* __restrict__ degc,
    const float* __restrict__ cw, const float* __restrict__ cb,
    const float* __restrict__ sw, const float* __restrict__ sb,
    __hip_bfloat16* __restrict__ gHi, __hip_bfloat16* __restrict__ gLo,
    float* __restrict__ xselfT) {
  const int lane = threadIdx.x & 63;
  const int wv = threadIdx.x >> 6;
  const int s = blockIdx.x * 64 + lane;
  const float xv = K[(size_t)s * NN + s];          // diag(K)
  const float ds = rsqrtf((float)degc[s]);
#pragma unroll
  for (int i = 0; i < 16; ++i) {
    const int c = wv * 16 + i;
    const float gv = ds * xv * cw[c];
    const __hip_bfloat16 hi = __float2bfloat16(gv);
    gHi[(size_t)c * NN + s] = hi;
    gLo[(size_t)c * NN + s] = __float2bfloat16(gv - __bfloat162float(hi));
    xselfT[(size_t)c * NN + s] = xv * sw[c] + sb[c] + cb[c];
  }
}

// ---------- layer 1/2 transform ----------
__global__ __launch_bounds__(256) void k_xform(const float* __restrict__ xoutT,
    const float* __restrict__ sk, const unsigned* __restrict__ degc,
    const float* __restrict__ cw, const float* __restrict__ cb,
    const float* __restrict__ sw, const float* __restrict__ sb,
    __hip_bfloat16* __restrict__ gHi, __hip_bfloat16* __restrict__ gLo,
    float* __restrict__ xselfT) {
  __shared__ float xt[64][64];                     // [k][s-local]
  const int lane = threadIdx.x & 63;
  const int wv = threadIdx.x >> 6;
  const int s = blockIdx.x * 64 + lane;
  const float skv = sk[s];
#pragma unroll
  for (int i = 0; i < 16; ++i) {
    const int k = wv * 16 + i;
    xt[k][lane] = xoutT[(size_t)k * NN + s] + skv; // coalesced
  }
  __syncthreads();
  const int cbase = blockIdx.y * 32 + wv * 8;
  float accC[8], accS[8];
#pragma unroll
  for (int i = 0; i < 8; ++i) { accC[i] = 0.f; accS[i] = 0.f; }
  for (int k = 0; k < 64; ++k) {
    const float xv = xt[k][lane];
#pragma unroll
    for (int i = 0; i < 8; ++i) {
      accC[i] = fmaf(xv, cw[k * 64 + cbase + i], accC[i]);
      accS[i] = fmaf(xv, sw[k * 64 + cbase + i], accS[i]);
    }
  }
  const float ds = rsqrtf((float)degc[s]);
#pragma unroll
  for (int i = 0; i < 8; ++i) {
    const int c = cbase + i;
    const float gv = ds * accC[i];
    const __hip_bfloat16 hi = __float2bfloat16(gv);
    gHi[(size_t)c * NN + s] = hi;
    gLo[(size_t)c * NN + s] = __float2bfloat16(gv - __bfloat162float(hi));
    xselfT[(size_t)c * NN + s] = accS[i] + sb[c] + cb[c];
  }
}

// ---------- MFMA masked aggregation, split-K partials ----------
__global__ __launch_bounds__(512) void k_agg(const unsigned long long* __restrict__ maskT,
    const __hip_bfloat16* __restrict__ gHi, const __hip_bfloat16* __restrict__ gLo,
    float* __restrict__ pacc, int cpk) {
  const int tid = threadIdx.x;
  const int lane = tid & 63;
  const int wv = tid >> 6;           // 0..7
  const int mtile = wv & 3;          // channel 16-group
  const int nhalf = wv >> 2;         // which 16 d's
  const int l15 = lane & 15;
  const int h = lane >> 4;           // 0..3
  const int d = blockIdx.x * 32 + nhalf * 16 + l15;
  const int ch = mtile * 16 + l15;   // A-operand row (channel)
  const int c0 = blockIdx.y * cpk;
  const short* __restrict__ gh = (const short*)gHi;
  const short* __restrict__ gl = (const short*)gLo;
  f32x4 acch = {0.f, 0.f, 0.f, 0.f};
  f32x4 accl = {0.f, 0.f, 0.f, 0.f};
#pragma unroll 4
  for (int c = c0; c < c0 + cpk; ++c) {
    const unsigned long long w = maskT[(size_t)c * NN + d];
    const unsigned half0 = (unsigned)w, half1 = (unsigned)(w >> 32);
#pragma unroll
    for (int t = 0; t < 2; ++t) {
      const unsigned half = t ? half1 : half0;
      const unsigned hb = (half >> (8 * h)) & 0xFFu;
      s16x8 bfr;
#pragma unroll
      for (int j = 0; j < 8; ++j)
        bfr[j] = (short)(((hb >> j) & 1u) * 0x3F80u);   // bit -> bf16 1.0/0.0
      const size_t abase = (size_t)ch * NN + (size_t)(c * 64 + t * 32 + 8 * h);
      const s16x8 ah = *(const s16x8*)(gh + abase);
      const s16x8 al = *(const s16x8*)(gl + abase);
      acch = __builtin_amdgcn_mfma_f32_16x16x32_bf16(ah, bfr, acch, 0, 0, 0);
      accl = __builtin_amdgcn_mfma_f32_16x16x32_bf16(al, bfr, accl, 0, 0, 0);
    }
  }
#pragma unroll
  for (int r = 0; r < 4; ++r) {
    const int chr = mtile * 16 + h * 4 + r;
    pacc[((size_t)blockIdx.y * 64 + chr) * NN + d] = acch[r] + accl[r];
  }
}

// ---------- combine partials + xself + dis, cls score v ----------
__global__ __launch_bounds__(256) void k_combine(const float* __restrict__ pacc, int nkb,
    const float* __restrict__ xselfT, const unsigned* __restrict__ degc,
    const float* __restrict__ kw, const float* __restrict__ kb,
    float* __restrict__ xoutT, float* __restrict__ v) {
  __shared__ float red[4][64];
  const int lane = threadIdx.x & 63;
  const int wv = threadIdx.x >> 6;
  const int d = blockIdx.x * 64 + lane;
  const float dd = rsqrtf((float)degc[d]);
  float p = 0.f;
#pragma unroll
  for (int i = 0; i < 16; ++i) {
    const int c = wv * 16 + i;
    float a = 0.f;
    for (int k2 = 0; k2 < nkb; ++k2) a += pacc[((size_t)k2 * 64 + c) * NN + d];
    const float xo = xselfT[(size_t)c * NN + d] + dd * a;
    xoutT[(size_t)c * NN + d] = xo;
    p = fmaf(xo, kw[c], p);
  }
  red[wv][lane] = p;
  __syncthreads();
  if (wv == 0) v[d] = red[0][lane] + red[1][lane] + red[2][lane] + red[3][lane] + kb[0];
}

// ---------- DPP-based 16-lane-group reduce-all ----------
#define DPP_SHR1 0x111
#define DPP_SHR2 0x112
#define DPP_SHR4 0x114
#define DPP_SHR8 0x118

template <int CTRL>
__device__ __forceinline__ float dpp_mov(float x, float oldv) {
  return __int_as_float(__builtin_amdgcn_update_dpp(
      __float_as_int(oldv), __float_as_int(x), CTRL, 0xf, 0xf, false));
}

__device__ __forceinline__ float grp16_bcast15(float x) {
  // BitMode swizzle: new_lane = (lane & 0x10) | 0x0F -> lane 15 of each 16-group
  return __int_as_float(__builtin_amdgcn_ds_swizzle(__float_as_int(x), 0x01F0));
}

__device__ __forceinline__ float grp16_max(float x) {
  x = fmaxf(x, dpp_mov<DPP_SHR1>(x, x));
  x = fmaxf(x, dpp_mov<DPP_SHR2>(x, x));
  x = fmaxf(x, dpp_mov<DPP_SHR4>(x, x));
  x = fmaxf(x, dpp_mov<DPP_SHR8>(x, x));
  return grp16_bcast15(x);     // lane15 holds group max
}

__device__ __forceinline__ float grp16_sum(float x) {
  x = x + dpp_mov<DPP_SHR1>(x, 0.0f);
  x = x + dpp_mov<DPP_SHR2>(x, 0.0f);
  x = x + dpp_mov<DPP_SHR4>(x, 0.0f);
  x = x + dpp_mov<DPP_SHR8>(x, 0.0f);
  return grp16_bcast15(x);     // lane15 holds group sum
}

// ---------- log-domain Sinkhorn: in -> 20 iters -> out = exp(m) ----------
// thread t owns 4 elements of row/col (t>>4); 16-lane-group LSE via DPP.
__global__ __launch_bounds__(1024) void k_sinkhorn(const float* __restrict__ in,
                                                   float* __restrict__ outp,
                                                   float scale) {
  __shared__ float m[64][65];
  const int t = threadIdx.x;
  const int g = t >> 4;        // row (even its) / col (odd its)
  const int q = t & 15;
#pragma unroll
  for (int j = 0; j < 4; ++j) {
    const int e = 4 * t + j;
    m[e >> 6][e & 63] = in[e] * scale;
  }
  __syncthreads();
  for (int it = 0; it < 20; ++it) {
    float x0, x1, x2, x3;
    if ((it & 1) == 0) {
      x0 = m[g][4 * q + 0]; x1 = m[g][4 * q + 1];
      x2 = m[g][4 * q + 2]; x3 = m[g][4 * q + 3];
    } else {
      x0 = m[4 * q + 0][g]; x1 = m[4 * q + 1][g];
      x2 = m[4 * q + 2][g]; x3 = m[4 * q + 3][g];
    }
    const float mx = grp16_max(fmaxf(fmaxf(x0, x1), fmaxf(x2, x3)));
    const float sm = grp16_sum((__expf(x0 - mx) + __expf(x1 - mx)) +
                               (__expf(x2 - mx) + __expf(x3 - mx)));
    const float lse = mx + __logf(sm);
    x0 -= lse; x1 -= lse; x2 -= lse; x3 -= lse;
    if ((it & 1) == 0) {
      m[g][4 * q + 0] = x0; m[g][4 * q + 1] = x1;
      m[g][4 * q + 2] = x2; m[g][4 * q + 3] = x3;
    } else {
      m[4 * q + 0][g] = x0; m[4 * q + 1][g] = x1;
      m[4 * q + 2][g] = x2; m[4 * q + 3][g] = x3;
    }
    __syncthreads();
  }
#pragma unroll
  for (int j = 0; j < 4; ++j) {
    const int e = 4 * t + j;
    outp[e] = __expf(m[e >> 6][e & 63]);
  }
}

// ---------- final scores (parallel): sT[(n&63)*64 + (n>>6)] = 20*(x@fw + fb) ----------
__global__ __launch_bounds__(256) void k_score(const float* __restrict__ xoutT,
    const float* __restrict__ sk, const float* __restrict__ fw,
    const float* __restrict__ fb, float* __restrict__ sT) {
  const int n = blockIdx.x * 256 + threadIdx.x;
  float acc = 0.f, sumw = 0.f;
#pragma unroll 8
  for (int k = 0; k < 64; ++k) {
    const float w = fw[k];
    sumw += w;
    acc = fmaf(xoutT[(size_t)k * NN + n], w, acc);
  }
  const float sc = (acc + sk[n] * sumw + fb[0]) * 20.0f;
  sT[(n & 63) * 64 + (n >> 6)] = sc;    // s = scores.reshape(n2,n1).T, pre-scaled
}

extern "C" void kernel_launch(void* const* d_in, const int* in_sizes, int n_in,
                              void* d_out, int out_size, void* d_ws, size_t ws_size,
                              hipStream_t stream) {
  const float* K = (const float*)d_in[0];
  const float* cw[3] = {(const float*)d_in[4],  (const float*)d_in[10], (const float*)d_in[16]};
  const float* cb[3] = {(const float*)d_in[5],  (const float*)d_in[11], (const float*)d_in[17]};
  const float* sw[3] = {(const float*)d_in[6],  (const float*)d_in[12], (const float*)d_in[18]};
  const float* sb[3] = {(const float*)d_in[7],  (const float*)d_in[13], (const float*)d_in[19]};
  const float* kw[3] = {(const float*)d_in[8],  (const float*)d_in[14], (const float*)d_in[20]};
  const float* kb[3] = {(const float*)d_in[9],  (const float*)d_in[15], (const float*)d_in[21]};
  const float* fw = (const float*)d_in[22];
  const float* fb = (const float*)d_in[23];
  float* out = (float*)d_out;

  char* ws = (char*)d_ws;
  const size_t KB = 1024, MB = 1024 * 1024;
  unsigned* degc            = (unsigned*)(ws + 0);                // 16 KB
  float* v                  = (float*)(ws + 16 * KB);             // 16 KB
  float* sk                 = (float*)(ws + 32 * KB);             // 16 KB
  float* sT                 = (float*)(ws + 48 * KB);             // 16 KB
  unsigned long long* maskT = (unsigned long long*)(ws + 64 * KB);// 2 MB
  __hip_bfloat16* gHi       = (__hip_bfloat16*)(ws + 64 * KB + 2 * MB);            // 512 KB
  __hip_bfloat16* gLo       = (__hip_bfloat16*)(ws + 64 * KB + 2 * MB + 512 * KB); // 512 KB
  float* xselfT             = (float*)(ws + 64 * KB + 3 * MB);    // 1 MB
  float* xoutT              = (float*)(ws + 64 * KB + 4 * MB);    // 1 MB
  float* pacc               = (float*)(ws + 64 * KB + 5 * MB);    // NKB MB
  (void)in_sizes; (void)n_in; (void)out_size;

  int NKB = 8;
  while (NKB > 1 && 64 * KB + (5 + (size_t)NKB) * MB > ws_size) NKB >>= 1;
  const int cpk = 64 / NKB;

  hipMemsetAsync(degc, 0, NN * sizeof(unsigned), stream);
  k_prep<<<dim3(16, 16), 256, 0, stream>>>(K, degc, maskT);

  for (int l = 0; l < 3; ++l) {
    if (l == 0)
      k_xform0<<<64, 256, 0, stream>>>(K, degc, cw[0], cb[0], sw[0], sb[0], gHi, gLo, xselfT);
    else
      k_xform<<<dim3(64, 2), 256, 0, stream>>>(xoutT, sk, degc, cw[l], cb[l], sw[l], sb[l], gHi, gLo, xselfT);
    k_agg<<<dim3(128, NKB), 512, 0, stream>>>(maskT, gHi, gLo, pacc, cpk);
    k_combine<<<64, 256, 0, stream>>>(pacc, NKB, xselfT, degc, kw[l], kb[l], xoutT, v);
    k_sinkhorn<<<1, 1024, 0, stream>>>(v, sk, 20.0f);
  }
  k_score<<<16, 256, 0, stream>>>(xoutT, sk, fw, fb, sT);
  k_sinkhorn<<<1, 1024, 0, stream>>>(sT, out, 1.0f);
}